// Round 4
// baseline (710.488 us; speedup 1.0000x reference)
//
#include <hip/hip_runtime.h>
#include <hip/hip_bf16.h>

#define SEQ 49
#define CH 768
#define NH 24
#define HD 32
#define NB 1024
#define NWIN 64
#define MTOT (NB*SEQ)      // 50176
#define K3 (3*CH)          // 2304

typedef __hip_bfloat16 bf16;
typedef __attribute__((ext_vector_type(8))) short short8;
typedef __attribute__((ext_vector_type(4))) short short4v;
typedef __attribute__((ext_vector_type(4))) float f32x4;

#define MD  ((size_t)MTOT * HD)     // elems per head plane: 1,605,632
#define NHMD ((size_t)NH * MD)      // elems per q/k/v section

__device__ __forceinline__ void gload16(const void* g, void* l) {
  __builtin_amdgcn_global_load_lds((__attribute__((address_space(1))) void*)g,
                                   (__attribute__((address_space(3))) void*)l,
                                   16, 0, 0);
}

__device__ __forceinline__ float bf2f(short s) {
  return __uint_as_float(((unsigned int)(unsigned short)s) << 16);
}

// ---------------- converters ----------------
__global__ void cvt_bf16(const float* __restrict__ in, bf16* __restrict__ o, int n4) {
  int i = blockIdx.x * blockDim.x + threadIdx.x;
  if (i >= n4) return;
  float4 v = ((const float4*)in)[i];
  union { bf16 b[4]; short4 s; } u;
  u.b[0] = __float2bfloat16(v.x);
  u.b[1] = __float2bfloat16(v.y);
  u.b[2] = __float2bfloat16(v.z);
  u.b[3] = __float2bfloat16(v.w);
  ((short4*)o)[i] = u.s;
}

// comb[s][h][mn] = rel_bias_table[rpi[mn]][h] + shift_mask[s][mn]
__global__ void build_comb(const float* __restrict__ table, const int* __restrict__ rpi,
                           const float* __restrict__ smask, float* __restrict__ comb) {
  int i = blockIdx.x * blockDim.x + threadIdx.x;
  if (i >= NWIN * NH * SEQ * SEQ) return;
  int mn = i % (SEQ * SEQ);
  int sh = i / (SEQ * SEQ);
  int h = sh % NH;
  int s = sh / NH;
  comb[i] = table[rpi[mn] * NH + h] + smask[s * SEQ * SEQ + mn];
}

// ================= GEMM core (128x128 tile, BK=64, T2 swizzle) =================
// A[M][768], Bw[N][768] row-major; per-thread: 4+4 gload16 staging with
// pre-swizzled source (chunk ^= row&7), swizzled ds_read (same involution).

// ---------------- kernel 1: QKV GEMM -> qkvT[sec][head][M][32] ----------------
__global__ __launch_bounds__(256) void qkv_gemm(
    const bf16* __restrict__ A, const bf16* __restrict__ Bw,
    const float* __restrict__ bias, bf16* __restrict__ C)
{
  __shared__ __align__(16) bf16 As[128 * 64];   // 16 KB
  __shared__ __align__(16) bf16 Bs[128 * 64];   // 16 KB
  const int tid = threadIdx.x;
  const int w = tid >> 6, l = tid & 63;
  const int lr = l & 15, lg = l >> 4;
  const int wm = w >> 1, wn = w & 1;
  const int bn = blockIdx.x, bm = blockIdx.y;   // TRANSPOSED: bn fastest -> A-panel L2 reuse

  // staging: load j covers rows j*32 + tid/8, chunk tid&7 (16B chunks, 8/row)
  const int srow0 = tid >> 3;        // 0..31
  const int chk = tid & 7;
  const bf16* gA[4];
  const bf16* gB[4];
#pragma unroll
  for (int j = 0; j < 4; j++) {
    int row = j * 32 + srow0;
    int srcch = chk ^ (row & 7);
    gA[j] = A + ((size_t)(bm * 128 + row)) * CH + srcch * 8;
    gB[j] = Bw + ((size_t)(bn * 128 + row)) * CH + srcch * 8;
  }

  f32x4 acc[4][4];
  f32x4 zero4 = {0.f, 0.f, 0.f, 0.f};
#pragma unroll
  for (int i = 0; i < 4; i++)
#pragma unroll
    for (int j = 0; j < 4; j++) acc[i][j] = zero4;

  // precomputed swizzled LDS read offsets (elements)
  int offA[4][2], offB[4][2];
#pragma unroll
  for (int mi = 0; mi < 4; mi++) {
#pragma unroll
    for (int ks = 0; ks < 2; ks++) {
      int rowa = 64 * wm + 16 * mi + lr;
      offA[mi][ks] = rowa * 64 + ((lg + 4 * ks) ^ (rowa & 7)) * 8;
      int rowb = 64 * wn + 16 * mi + lr;
      offB[mi][ks] = rowb * 64 + ((lg + 4 * ks) ^ (rowb & 7)) * 8;
    }
  }

  for (int kk = 0; kk < CH; kk += 64) {
#pragma unroll
    for (int j = 0; j < 4; j++) gload16(gA[j] + kk, As + j * 2048 + tid * 8);
#pragma unroll
    for (int j = 0; j < 4; j++) gload16(gB[j] + kk, Bs + j * 2048 + tid * 8);
    __syncthreads();
    short8 af[4][2], bfv[4][2];
#pragma unroll
    for (int mi = 0; mi < 4; mi++)
#pragma unroll
      for (int ks = 0; ks < 2; ks++) {
        af[mi][ks] = *(const short8*)(As + offA[mi][ks]);
        bfv[mi][ks] = *(const short8*)(Bs + offB[mi][ks]);
      }
#pragma unroll
    for (int ks = 0; ks < 2; ks++)
#pragma unroll
      for (int mi = 0; mi < 4; mi++)
#pragma unroll
        for (int nj = 0; nj < 4; nj++)
          acc[mi][nj] = __builtin_amdgcn_mfma_f32_16x16x32_bf16(af[mi][ks], bfv[nj][ks], acc[mi][nj], 0, 0, 0);
    __syncthreads();
  }

  const int colbase = bn * 128 + 64 * wn;
  const int rowbase = bm * 128 + 64 * wm;
#pragma unroll
  for (int nj = 0; nj < 4; nj++) {
    const int cb16 = colbase + 16 * nj;      // uniform per nj; never crosses a 32-col head
    const int sec = cb16 / 768;              // 0=q 1=k 2=v
    const int rem = cb16 - sec * 768;
    const int h = rem >> 5;
    const int dbase = rem & 31;              // 0 or 16
    float bv = bias[cb16 + lr];
    const size_t base = (size_t)sec * NHMD + (size_t)h * MD + dbase + lr;
#pragma unroll
    for (int mi = 0; mi < 4; mi++) {
#pragma unroll
      for (int r = 0; r < 4; r++) {
        size_t row = rowbase + 16 * mi + 4 * lg + r;
        C[base + row * HD] = __float2bfloat16(acc[mi][nj][r] + bv);
      }
    }
  }
}

// ---------------- kernel 2: attention ----------------
// grid (1024, 6), 256 threads; wave w handles head blockIdx.y*4 + w
__global__ __launch_bounds__(256) void attn_kernel(
    const bf16* __restrict__ qkvT, const float* __restrict__ comb,
    bf16* __restrict__ aout)
{
  __shared__ __align__(16) bf16 P[4][64 * 72];
  const int tid = threadIdx.x;
  const int w = tid >> 6, l = tid & 63;
  const int lr = l & 15, lg = l >> 4;
  const int b = blockIdx.x;
  const int h = blockIdx.y * 4 + w;
  const size_t rowb = (size_t)b * SEQ;
  const float scale = 0.17677669529663687f;  // 1/sqrt(32)
  f32x4 zero4 = {0.f, 0.f, 0.f, 0.f};

  // per-(window,head) contiguous tiles (49x32 bf16 = 3.1 KB each)
  const bf16* qb = qkvT + (size_t)h * MD + rowb * HD;
  const bf16* kb = qkvT + NHMD + (size_t)h * MD + rowb * HD;
  const bf16* vb = qkvT + 2 * NHMD + (size_t)h * MD + rowb * HD;

  short8 qf[4], kf[4];
#pragma unroll
  for (int mt = 0; mt < 4; mt++)
    qf[mt] = *(const short8*)(qb + (16 * mt + lr) * HD + 8 * lg);
#pragma unroll
  for (int nt = 0; nt < 4; nt++)
    kf[nt] = *(const short8*)(kb + (16 * nt + lr) * HD + 8 * lg);

  f32x4 s[4][4];
#pragma unroll
  for (int mt = 0; mt < 4; mt++)
#pragma unroll
    for (int nt = 0; nt < 4; nt++)
      s[mt][nt] = __builtin_amdgcn_mfma_f32_16x16x32_bf16(qf[mt], kf[nt], zero4, 0, 0, 0);

  const short* vs = (const short*)vb;
  short8 pb[2][2];
#pragma unroll
  for (int kt = 0; kt < 2; kt++)
#pragma unroll
    for (int dt = 0; dt < 2; dt++) {
      short8 t;
#pragma unroll
      for (int j = 0; j < 8; j++) {
        int n = 32 * kt + 8 * lg + j;
        short val = 0;
        if (n < SEQ) val = vs[n * HD + 16 * dt + lr];
        t[j] = val;
      }
      pb[kt][dt] = t;
    }

  const float* cb = comb + ((size_t)((b & (NWIN - 1)) * NH + h)) * (SEQ * SEQ);
#pragma unroll
  for (int mt = 0; mt < 4; mt++)
#pragma unroll
    for (int nt = 0; nt < 4; nt++)
#pragma unroll
      for (int r = 0; r < 4; r++) {
        int m = 16 * mt + 4 * lg + r, n = 16 * nt + lr;
        float v;
        if (m < SEQ && n < SEQ) v = s[mt][nt][r] * scale + cb[m * SEQ + n];
        else v = -1e30f;
        s[mt][nt][r] = v;
      }

  float mx[4][4];
#pragma unroll
  for (int mt = 0; mt < 4; mt++)
#pragma unroll
    for (int r = 0; r < 4; r++) {
      float m0 = fmaxf(fmaxf(s[mt][0][r], s[mt][1][r]), fmaxf(s[mt][2][r], s[mt][3][r]));
      m0 = fmaxf(m0, __shfl_xor(m0, 1, 64));
      m0 = fmaxf(m0, __shfl_xor(m0, 2, 64));
      m0 = fmaxf(m0, __shfl_xor(m0, 4, 64));
      m0 = fmaxf(m0, __shfl_xor(m0, 8, 64));
      mx[mt][r] = m0;
    }
  float inv[4][4];
#pragma unroll
  for (int mt = 0; mt < 4; mt++)
#pragma unroll
    for (int r = 0; r < 4; r++) {
      float t = 0.f;
#pragma unroll
      for (int nt = 0; nt < 4; nt++) {
        float e = __expf(s[mt][nt][r] - mx[mt][r]);
        s[mt][nt][r] = e;
        t += e;
      }
      t += __shfl_xor(t, 1, 64);
      t += __shfl_xor(t, 2, 64);
      t += __shfl_xor(t, 4, 64);
      t += __shfl_xor(t, 8, 64);
      inv[mt][r] = 1.0f / t;
    }

#pragma unroll
  for (int mt = 0; mt < 4; mt++)
#pragma unroll
    for (int nt = 0; nt < 4; nt++)
#pragma unroll
      for (int r = 0; r < 4; r++)
        P[w][(16 * mt + 4 * lg + r) * 72 + 16 * nt + lr] =
            __float2bfloat16(s[mt][nt][r] * inv[mt][r]);

  f32x4 o[4][2];
#pragma unroll
  for (int mt = 0; mt < 4; mt++) { o[mt][0] = zero4; o[mt][1] = zero4; }
#pragma unroll
  for (int kt = 0; kt < 2; kt++) {
    short8 pa[4];
#pragma unroll
    for (int mt = 0; mt < 4; mt++)
      pa[mt] = *(const short8*)(&P[w][(16 * mt + lr) * 72 + 32 * kt + 8 * lg]);
#pragma unroll
    for (int mt = 0; mt < 4; mt++)
#pragma unroll
      for (int dt = 0; dt < 2; dt++)
        o[mt][dt] = __builtin_amdgcn_mfma_f32_16x16x32_bf16(pa[mt], pb[kt][dt], o[mt][dt], 0, 0, 0);
  }

#pragma unroll
  for (int mt = 0; mt < 4; mt++)
#pragma unroll
    for (int dt = 0; dt < 2; dt++)
#pragma unroll
      for (int r = 0; r < 4; r++) {
        int m = 16 * mt + 4 * lg + r;
        if (m < SEQ)
          aout[(rowb + m) * CH + h * HD + 16 * dt + lr] = __float2bfloat16(o[mt][dt][r]);
      }
}

// ---------------- kernel 3: proj GEMM + bias + residual ----------------
// Y[M][768] (bf16) = A[M][768] @ Wp[768][768]^T + bias + x
__global__ __launch_bounds__(256) void proj_gemm(
    const bf16* __restrict__ A, const bf16* __restrict__ Bw,
    const float* __restrict__ bias, const float* __restrict__ x,
    bf16* __restrict__ Y)
{
  __shared__ __align__(16) bf16 As[128 * 64];
  __shared__ __align__(16) bf16 Bs[128 * 64];
  const int tid = threadIdx.x;
  const int w = tid >> 6, l = tid & 63;
  const int lr = l & 15, lg = l >> 4;
  const int wm = w >> 1, wn = w & 1;
  const int bn = blockIdx.x, bm = blockIdx.y;   // transposed grid

  const int srow0 = tid >> 3;
  const int chk = tid & 7;
  const bf16* gA[4];
  const bf16* gB[4];
#pragma unroll
  for (int j = 0; j < 4; j++) {
    int row = j * 32 + srow0;
    int srcch = chk ^ (row & 7);
    gA[j] = A + ((size_t)(bm * 128 + row)) * CH + srcch * 8;
    gB[j] = Bw + ((size_t)(bn * 128 + row)) * CH + srcch * 8;
  }

  f32x4 acc[4][4];
  f32x4 zero4 = {0.f, 0.f, 0.f, 0.f};
#pragma unroll
  for (int i = 0; i < 4; i++)
#pragma unroll
    for (int j = 0; j < 4; j++) acc[i][j] = zero4;

  int offA[4][2], offB[4][2];
#pragma unroll
  for (int mi = 0; mi < 4; mi++) {
#pragma unroll
    for (int ks = 0; ks < 2; ks++) {
      int rowa = 64 * wm + 16 * mi + lr;
      offA[mi][ks] = rowa * 64 + ((lg + 4 * ks) ^ (rowa & 7)) * 8;
      int rowb = 64 * wn + 16 * mi + lr;
      offB[mi][ks] = rowb * 64 + ((lg + 4 * ks) ^ (rowb & 7)) * 8;
    }
  }

  for (int kk = 0; kk < CH; kk += 64) {
#pragma unroll
    for (int j = 0; j < 4; j++) gload16(gA[j] + kk, As + j * 2048 + tid * 8);
#pragma unroll
    for (int j = 0; j < 4; j++) gload16(gB[j] + kk, Bs + j * 2048 + tid * 8);
    __syncthreads();
    short8 af[4][2], bfv[4][2];
#pragma unroll
    for (int mi = 0; mi < 4; mi++)
#pragma unroll
      for (int ks = 0; ks < 2; ks++) {
        af[mi][ks] = *(const short8*)(As + offA[mi][ks]);
        bfv[mi][ks] = *(const short8*)(Bs + offB[mi][ks]);
      }
#pragma unroll
    for (int ks = 0; ks < 2; ks++)
#pragma unroll
      for (int mi = 0; mi < 4; mi++)
#pragma unroll
        for (int nj = 0; nj < 4; nj++)
          acc[mi][nj] = __builtin_amdgcn_mfma_f32_16x16x32_bf16(af[mi][ks], bfv[nj][ks], acc[mi][nj], 0, 0, 0);
    __syncthreads();
  }

  const int colbase = bn * 128 + 64 * wn;
  const int rowbase = bm * 128 + 64 * wm;
#pragma unroll
  for (int nj = 0; nj < 4; nj++) {
    int col = colbase + 16 * nj + lr;
    float bv = bias[col];
#pragma unroll
    for (int mi = 0; mi < 4; mi++) {
#pragma unroll
      for (int r = 0; r < 4; r++) {
        size_t row = rowbase + 16 * mi + 4 * lg + r;
        float v = acc[mi][nj][r] + bv + x[row * CH + col];
        Y[row * CH + col] = __float2bfloat16(v);
      }
    }
  }
}

// ---------------- kernel 4: LayerNorm ----------------
__global__ __launch_bounds__(256) void ln_kernel(
    const bf16* __restrict__ Y, const float* __restrict__ g,
    const float* __restrict__ be, float* __restrict__ out)
{
  const int w = threadIdx.x >> 6, l = threadIdx.x & 63;
  const size_t r = (size_t)blockIdx.x * 4 + w;
  const bf16* yr = Y + r * CH;

  short8 a = *(const short8*)(yr + 8 * l);
  short4v b4 = *(const short4v*)(yr + 512 + 4 * l);
  float v[12];
#pragma unroll
  for (int j = 0; j < 8; j++) v[j] = bf2f(a[j]);
#pragma unroll
  for (int j = 0; j < 4; j++) v[8 + j] = bf2f(b4[j]);

  float s1 = 0.f, s2 = 0.f;
#pragma unroll
  for (int j = 0; j < 12; j++) { s1 += v[j]; s2 += v[j] * v[j]; }
#pragma unroll
  for (int m = 1; m <= 32; m <<= 1) {
    s1 += __shfl_xor(s1, m, 64);
    s2 += __shfl_xor(s2, m, 64);
  }
  float mu = s1 * (1.0f / 768.0f);
  float var = s2 * (1.0f / 768.0f) - mu * mu;
  float rs = rsqrtf(var + 1e-5f);

  float4 g0 = *(const float4*)(g + 8 * l);
  float4 g1 = *(const float4*)(g + 8 * l + 4);
  float4 g2 = *(const float4*)(g + 512 + 4 * l);
  float4 b0 = *(const float4*)(be + 8 * l);
  float4 b1 = *(const float4*)(be + 8 * l + 4);
  float4 b2 = *(const float4*)(be + 512 + 4 * l);

  float4 o0, o1, o2;
  o0.x = (v[0] - mu) * rs * g0.x + b0.x;
  o0.y = (v[1] - mu) * rs * g0.y + b0.y;
  o0.z = (v[2] - mu) * rs * g0.z + b0.z;
  o0.w = (v[3] - mu) * rs * g0.w + b0.w;
  o1.x = (v[4] - mu) * rs * g1.x + b1.x;
  o1.y = (v[5] - mu) * rs * g1.y + b1.y;
  o1.z = (v[6] - mu) * rs * g1.z + b1.z;
  o1.w = (v[7] - mu) * rs * g1.w + b1.w;
  o2.x = (v[8] - mu) * rs * g2.x + b2.x;
  o2.y = (v[9] - mu) * rs * g2.y + b2.y;
  o2.z = (v[10] - mu) * rs * g2.z + b2.z;
  o2.w = (v[11] - mu) * rs * g2.w + b2.w;

  float* orow = out + r * CH;
  *(float4*)(orow + 8 * l) = o0;
  *(float4*)(orow + 8 * l + 4) = o1;
  *(float4*)(orow + 512 + 4 * l) = o2;
}

// ---------------- launch ----------------
extern "C" void kernel_launch(void* const* d_in, const int* in_sizes, int n_in,
                              void* d_out, int out_size, void* d_ws, size_t ws_size,
                              hipStream_t stream) {
  (void)in_sizes; (void)n_in; (void)out_size; (void)ws_size;
  const float* x     = (const float*)d_in[0];
  const float* smask = (const float*)d_in[1];
  const float* wqkv  = (const float*)d_in[2];
  const float* bqkv  = (const float*)d_in[3];
  const float* wproj = (const float*)d_in[4];
  const float* bproj = (const float*)d_in[5];
  const float* table = (const float*)d_in[6];
  const float* lng   = (const float*)d_in[7];
  const float* lnb   = (const float*)d_in[8];
  const int*   rpi   = (const int*)d_in[9];
  float* out = (float*)d_out;

  char* ws = (char*)d_ws;
  bf16*  xb   = (bf16*)(ws);                      // 77,070,336 B
  bf16*  wqb  = (bf16*)(ws + 77070336);           //  3,538,944 B
  bf16*  wpb  = (bf16*)(ws + 80609280);           //  1,179,648 B
  float* comb = (float*)(ws + 81788928);          // 14,745,600 B
  bf16*  qkvT = (bf16*)(ws + 96534528);           // 231,211,008 B
  bf16*  aout = (bf16*)(ws + 327745536);          // 77,070,336 B
  bf16*  yb   = (bf16*)(ws + 96534528);           // aliases qkvT (dead after attn)

  cvt_bf16<<<37632, 256, 0, stream>>>(x, xb, 9633792);
  cvt_bf16<<<1728, 256, 0, stream>>>(wqkv, wqb, 442368);
  cvt_bf16<<<576, 256, 0, stream>>>(wproj, wpb, 147456);
  build_comb<<<14400, 256, 0, stream>>>(table, rpi, smask, comb);
  qkv_gemm<<<dim3(18, 392), 256, 0, stream>>>(xb, wqb, bqkv, qkvT);
  attn_kernel<<<dim3(1024, 6), 256, 0, stream>>>(qkvT, comb, aout);
  proj_gemm<<<dim3(6, 392), 256, 0, stream>>>(aout, wpb, bproj, x, yb);
  ln_kernel<<<12544, 256, 0, stream>>>(yb, lng, lnb, out);
}

// Round 5
// 593.546 us; speedup vs baseline: 1.1970x; 1.1970x over previous
//
#include <hip/hip_runtime.h>
#include <hip/hip_bf16.h>

#define SEQ 49
#define CH 768
#define NH 24
#define HD 32
#define NB 1024
#define NWIN 64
#define MTOT (NB*SEQ)      // 50176
#define K3 (3*CH)          // 2304

typedef __hip_bfloat16 bf16;
typedef __attribute__((ext_vector_type(8))) short short8;
typedef __attribute__((ext_vector_type(4))) short short4v;
typedef __attribute__((ext_vector_type(4))) float f32x4;

#define MD  ((size_t)MTOT * HD)     // elems per head plane: 1,605,632
#define NHMD ((size_t)NH * MD)      // elems per q/k/v section

__device__ __forceinline__ void gload16(const void* g, void* l) {
  __builtin_amdgcn_global_load_lds((__attribute__((address_space(1))) void*)g,
                                   (__attribute__((address_space(3))) void*)l,
                                   16, 0, 0);
}

__device__ __forceinline__ float bf2f(short s) {
  return __uint_as_float(((unsigned int)(unsigned short)s) << 16);
}

// ---------------- converters ----------------
__global__ void cvt_bf16(const float* __restrict__ in, bf16* __restrict__ o, int n4) {
  int i = blockIdx.x * blockDim.x + threadIdx.x;
  if (i >= n4) return;
  float4 v = ((const float4*)in)[i];
  union { bf16 b[4]; short4 s; } u;
  u.b[0] = __float2bfloat16(v.x);
  u.b[1] = __float2bfloat16(v.y);
  u.b[2] = __float2bfloat16(v.z);
  u.b[3] = __float2bfloat16(v.w);
  ((short4*)o)[i] = u.s;
}

// comb[s][h][mn] = rel_bias_table[rpi[mn]][h] + shift_mask[s][mn]
__global__ void build_comb(const float* __restrict__ table, const int* __restrict__ rpi,
                           const float* __restrict__ smask, float* __restrict__ comb) {
  int i = blockIdx.x * blockDim.x + threadIdx.x;
  if (i >= NWIN * NH * SEQ * SEQ) return;
  int mn = i % (SEQ * SEQ);
  int sh = i / (SEQ * SEQ);
  int h = sh % NH;
  int s = sh / NH;
  comb[i] = table[rpi[mn] * NH + h] + smask[s * SEQ * SEQ + mn];
}

// ================= GEMM core: 128x128 tile, BK=64, T2 swizzle, =================
// 2-phase double-buffered pipeline (T3-min) + XCD-chunked block swizzle (T1).

// ---------------- kernel 1: QKV GEMM -> qkvT[sec][head][M][32] ----------------
// grid: 7056 blocks 1-D; logical wg -> (bm, bn) with bn fastest, XCD-chunked.
__global__ __launch_bounds__(256) void qkv_gemm(
    const bf16* __restrict__ A, const bf16* __restrict__ Bw,
    const float* __restrict__ bias, bf16* __restrict__ C)
{
  __shared__ __align__(16) bf16 As[2 * 128 * 64];   // 32 KB (double-buffered)
  __shared__ __align__(16) bf16 Bs[2 * 128 * 64];   // 32 KB
  const int tid = threadIdx.x;
  const int w = tid >> 6, l = tid & 63;
  const int lr = l & 15, lg = l >> 4;
  const int wm = w >> 1, wn = w & 1;

  // XCD-chunk swizzle: each XCD gets a contiguous 882-range (49 bm x 18 bn)
  const int flat = blockIdx.x;
  const int wg = (flat & 7) * 882 + (flat >> 3);
  const int bm = wg / 18, bn = wg - 18 * (wg / 18);

  // staging: chunk c = j*256+tid; row=c>>3, chk=c&7; pre-swizzled source chunk
  const int srow0 = tid >> 3;
  const int chk = tid & 7;
  const bf16* gA[4];
  const bf16* gB[4];
#pragma unroll
  for (int j = 0; j < 4; j++) {
    int row = j * 32 + srow0;
    int srcch = chk ^ (row & 7);
    gA[j] = A + ((size_t)(bm * 128 + row)) * CH + srcch * 8;
    gB[j] = Bw + ((size_t)(bn * 128 + row)) * CH + srcch * 8;
  }

  f32x4 acc[4][4];
  f32x4 zero4 = {0.f, 0.f, 0.f, 0.f};
#pragma unroll
  for (int i = 0; i < 4; i++)
#pragma unroll
    for (int j = 0; j < 4; j++) acc[i][j] = zero4;

  // swizzled LDS read offsets (elements)
  int offA[4][2], offB[4][2];
#pragma unroll
  for (int mi = 0; mi < 4; mi++) {
#pragma unroll
    for (int ks = 0; ks < 2; ks++) {
      int rowa = 64 * wm + 16 * mi + lr;
      offA[mi][ks] = rowa * 64 + ((lg + 4 * ks) ^ (rowa & 7)) * 8;
      int rowb = 64 * wn + 16 * mi + lr;
      offB[mi][ks] = rowb * 64 + ((lg + 4 * ks) ^ (rowb & 7)) * 8;
    }
  }

  // prologue: stage K-tile 0 into buffer 0
#pragma unroll
  for (int j = 0; j < 4; j++) gload16(gA[j], As + j * 2048 + tid * 8);
#pragma unroll
  for (int j = 0; j < 4; j++) gload16(gB[j], Bs + j * 2048 + tid * 8);
  __syncthreads();

  int cur = 0;
  for (int t = 0; t < 12; ++t) {
    const bf16* cA = As + cur * 8192;
    const bf16* cB = Bs + cur * 8192;
    if (t < 11) {                       // issue next-tile loads BEFORE compute
      const int kk = (t + 1) * 64;
      bf16* nA = As + (cur ^ 1) * 8192;
      bf16* nB = Bs + (cur ^ 1) * 8192;
#pragma unroll
      for (int j = 0; j < 4; j++) gload16(gA[j] + kk, nA + j * 2048 + tid * 8);
#pragma unroll
      for (int j = 0; j < 4; j++) gload16(gB[j] + kk, nB + j * 2048 + tid * 8);
    }
    short8 af[4][2], bfv[4][2];
#pragma unroll
    for (int mi = 0; mi < 4; mi++)
#pragma unroll
      for (int ks = 0; ks < 2; ks++) {
        af[mi][ks] = *(const short8*)(cA + offA[mi][ks]);
        bfv[mi][ks] = *(const short8*)(cB + offB[mi][ks]);
      }
    __builtin_amdgcn_s_setprio(1);
#pragma unroll
    for (int ks = 0; ks < 2; ks++)
#pragma unroll
      for (int mi = 0; mi < 4; mi++)
#pragma unroll
        for (int nj = 0; nj < 4; nj++)
          acc[mi][nj] = __builtin_amdgcn_mfma_f32_16x16x32_bf16(af[mi][ks], bfv[nj][ks], acc[mi][nj], 0, 0, 0);
    __builtin_amdgcn_s_setprio(0);
    __syncthreads();                    // vmcnt(0)+lgkmcnt(0) drain, then flip
    cur ^= 1;
  }

  const int colbase = bn * 128 + 64 * wn;
  const int rowbase = bm * 128 + 64 * wm;
#pragma unroll
  for (int nj = 0; nj < 4; nj++) {
    const int cb16 = colbase + 16 * nj;      // uniform per nj; never crosses a 32-col head
    const int sec = cb16 / 768;              // 0=q 1=k 2=v
    const int rem = cb16 - sec * 768;
    const int h = rem >> 5;
    const int dbase = rem & 31;              // 0 or 16
    float bv = bias[cb16 + lr];
    const size_t base = (size_t)sec * NHMD + (size_t)h * MD + dbase + lr;
#pragma unroll
    for (int mi = 0; mi < 4; mi++) {
#pragma unroll
      for (int r = 0; r < 4; r++) {
        size_t row = rowbase + 16 * mi + 4 * lg + r;
        C[base + row * HD] = __float2bfloat16(acc[mi][nj][r] + bv);
      }
    }
  }
}

// ---------------- kernel 2: attention ----------------
// grid (1024, 6), 256 threads; wave w handles head blockIdx.y*4 + w
__global__ __launch_bounds__(256) void attn_kernel(
    const bf16* __restrict__ qkvT, const float* __restrict__ comb,
    bf16* __restrict__ aout)
{
  __shared__ __align__(16) bf16 P[4][64 * 72];
  const int tid = threadIdx.x;
  const int w = tid >> 6, l = tid & 63;
  const int lr = l & 15, lg = l >> 4;
  const int b = blockIdx.x;
  const int h = blockIdx.y * 4 + w;
  const size_t rowb = (size_t)b * SEQ;
  const float scale = 0.17677669529663687f;  // 1/sqrt(32)
  f32x4 zero4 = {0.f, 0.f, 0.f, 0.f};

  // per-(window,head) contiguous tiles (49x32 bf16 = 3.1 KB each)
  const bf16* qb = qkvT + (size_t)h * MD + rowb * HD;
  const bf16* kb = qkvT + NHMD + (size_t)h * MD + rowb * HD;
  const bf16* vb = qkvT + 2 * NHMD + (size_t)h * MD + rowb * HD;

  short8 qf[4], kf[4];
#pragma unroll
  for (int mt = 0; mt < 4; mt++)
    qf[mt] = *(const short8*)(qb + (16 * mt + lr) * HD + 8 * lg);
#pragma unroll
  for (int nt = 0; nt < 4; nt++)
    kf[nt] = *(const short8*)(kb + (16 * nt + lr) * HD + 8 * lg);

  f32x4 s[4][4];
#pragma unroll
  for (int mt = 0; mt < 4; mt++)
#pragma unroll
    for (int nt = 0; nt < 4; nt++)
      s[mt][nt] = __builtin_amdgcn_mfma_f32_16x16x32_bf16(qf[mt], kf[nt], zero4, 0, 0, 0);

  const short* vs = (const short*)vb;
  short8 pb[2][2];
#pragma unroll
  for (int kt = 0; kt < 2; kt++)
#pragma unroll
    for (int dt = 0; dt < 2; dt++) {
      short8 t;
#pragma unroll
      for (int j = 0; j < 8; j++) {
        int n = 32 * kt + 8 * lg + j;
        short val = 0;
        if (n < SEQ) val = vs[n * HD + 16 * dt + lr];
        t[j] = val;
      }
      pb[kt][dt] = t;
    }

  const float* cb = comb + ((size_t)((b & (NWIN - 1)) * NH + h)) * (SEQ * SEQ);
#pragma unroll
  for (int mt = 0; mt < 4; mt++)
#pragma unroll
    for (int nt = 0; nt < 4; nt++)
#pragma unroll
      for (int r = 0; r < 4; r++) {
        int m = 16 * mt + 4 * lg + r, n = 16 * nt + lr;
        float v;
        if (m < SEQ && n < SEQ) v = s[mt][nt][r] * scale + cb[m * SEQ + n];
        else v = -1e30f;
        s[mt][nt][r] = v;
      }

  float mx[4][4];
#pragma unroll
  for (int mt = 0; mt < 4; mt++)
#pragma unroll
    for (int r = 0; r < 4; r++) {
      float m0 = fmaxf(fmaxf(s[mt][0][r], s[mt][1][r]), fmaxf(s[mt][2][r], s[mt][3][r]));
      m0 = fmaxf(m0, __shfl_xor(m0, 1, 64));
      m0 = fmaxf(m0, __shfl_xor(m0, 2, 64));
      m0 = fmaxf(m0, __shfl_xor(m0, 4, 64));
      m0 = fmaxf(m0, __shfl_xor(m0, 8, 64));
      mx[mt][r] = m0;
    }
  float inv[4][4];
#pragma unroll
  for (int mt = 0; mt < 4; mt++)
#pragma unroll
    for (int r = 0; r < 4; r++) {
      float t = 0.f;
#pragma unroll
      for (int nt = 0; nt < 4; nt++) {
        float e = __expf(s[mt][nt][r] - mx[mt][r]);
        s[mt][nt][r] = e;
        t += e;
      }
      t += __shfl_xor(t, 1, 64);
      t += __shfl_xor(t, 2, 64);
      t += __shfl_xor(t, 4, 64);
      t += __shfl_xor(t, 8, 64);
      inv[mt][r] = 1.0f / t;
    }

#pragma unroll
  for (int mt = 0; mt < 4; mt++)
#pragma unroll
    for (int nt = 0; nt < 4; nt++)
#pragma unroll
      for (int r = 0; r < 4; r++)
        P[w][(16 * mt + 4 * lg + r) * 72 + 16 * nt + lr] =
            __float2bfloat16(s[mt][nt][r] * inv[mt][r]);

  f32x4 o[4][2];
#pragma unroll
  for (int mt = 0; mt < 4; mt++) { o[mt][0] = zero4; o[mt][1] = zero4; }
#pragma unroll
  for (int kt = 0; kt < 2; kt++) {
    short8 pa[4];
#pragma unroll
    for (int mt = 0; mt < 4; mt++)
      pa[mt] = *(const short8*)(&P[w][(16 * mt + lr) * 72 + 32 * kt + 8 * lg]);
#pragma unroll
    for (int mt = 0; mt < 4; mt++)
#pragma unroll
      for (int dt = 0; dt < 2; dt++)
        o[mt][dt] = __builtin_amdgcn_mfma_f32_16x16x32_bf16(pa[mt], pb[kt][dt], o[mt][dt], 0, 0, 0);
  }

#pragma unroll
  for (int mt = 0; mt < 4; mt++)
#pragma unroll
    for (int dt = 0; dt < 2; dt++)
#pragma unroll
      for (int r = 0; r < 4; r++) {
        int m = 16 * mt + 4 * lg + r;
        if (m < SEQ)
          aout[(rowb + m) * CH + h * HD + 16 * dt + lr] = __float2bfloat16(o[mt][dt][r]);
      }
}

// ---------------- kernel 3: proj GEMM + bias + residual ----------------
// grid: 2352 blocks 1-D, XCD-chunked; Y = A @ Wp^T + bias + x (bf16 out)
__global__ __launch_bounds__(256) void proj_gemm(
    const bf16* __restrict__ A, const bf16* __restrict__ Bw,
    const float* __restrict__ bias, const float* __restrict__ x,
    bf16* __restrict__ Y)
{
  __shared__ __align__(16) bf16 As[2 * 128 * 64];
  __shared__ __align__(16) bf16 Bs[2 * 128 * 64];
  const int tid = threadIdx.x;
  const int w = tid >> 6, l = tid & 63;
  const int lr = l & 15, lg = l >> 4;
  const int wm = w >> 1, wn = w & 1;

  const int flat = blockIdx.x;
  const int wg = (flat & 7) * 294 + (flat >> 3);
  const int bm = wg / 6, bn = wg - 6 * (wg / 6);

  const int srow0 = tid >> 3;
  const int chk = tid & 7;
  const bf16* gA[4];
  const bf16* gB[4];
#pragma unroll
  for (int j = 0; j < 4; j++) {
    int row = j * 32 + srow0;
    int srcch = chk ^ (row & 7);
    gA[j] = A + ((size_t)(bm * 128 + row)) * CH + srcch * 8;
    gB[j] = Bw + ((size_t)(bn * 128 + row)) * CH + srcch * 8;
  }

  f32x4 acc[4][4];
  f32x4 zero4 = {0.f, 0.f, 0.f, 0.f};
#pragma unroll
  for (int i = 0; i < 4; i++)
#pragma unroll
    for (int j = 0; j < 4; j++) acc[i][j] = zero4;

  int offA[4][2], offB[4][2];
#pragma unroll
  for (int mi = 0; mi < 4; mi++) {
#pragma unroll
    for (int ks = 0; ks < 2; ks++) {
      int rowa = 64 * wm + 16 * mi + lr;
      offA[mi][ks] = rowa * 64 + ((lg + 4 * ks) ^ (rowa & 7)) * 8;
      int rowb = 64 * wn + 16 * mi + lr;
      offB[mi][ks] = rowb * 64 + ((lg + 4 * ks) ^ (rowb & 7)) * 8;
    }
  }

#pragma unroll
  for (int j = 0; j < 4; j++) gload16(gA[j], As + j * 2048 + tid * 8);
#pragma unroll
  for (int j = 0; j < 4; j++) gload16(gB[j], Bs + j * 2048 + tid * 8);
  __syncthreads();

  int cur = 0;
  for (int t = 0; t < 12; ++t) {
    const bf16* cA = As + cur * 8192;
    const bf16* cB = Bs + cur * 8192;
    if (t < 11) {
      const int kk = (t + 1) * 64;
      bf16* nA = As + (cur ^ 1) * 8192;
      bf16* nB = Bs + (cur ^ 1) * 8192;
#pragma unroll
      for (int j = 0; j < 4; j++) gload16(gA[j] + kk, nA + j * 2048 + tid * 8);
#pragma unroll
      for (int j = 0; j < 4; j++) gload16(gB[j] + kk, nB + j * 2048 + tid * 8);
    }
    short8 af[4][2], bfv[4][2];
#pragma unroll
    for (int mi = 0; mi < 4; mi++)
#pragma unroll
      for (int ks = 0; ks < 2; ks++) {
        af[mi][ks] = *(const short8*)(cA + offA[mi][ks]);
        bfv[mi][ks] = *(const short8*)(cB + offB[mi][ks]);
      }
    __builtin_amdgcn_s_setprio(1);
#pragma unroll
    for (int ks = 0; ks < 2; ks++)
#pragma unroll
      for (int mi = 0; mi < 4; mi++)
#pragma unroll
        for (int nj = 0; nj < 4; nj++)
          acc[mi][nj] = __builtin_amdgcn_mfma_f32_16x16x32_bf16(af[mi][ks], bfv[nj][ks], acc[mi][nj], 0, 0, 0);
    __builtin_amdgcn_s_setprio(0);
    __syncthreads();
    cur ^= 1;
  }

  const int colbase = bn * 128 + 64 * wn;
  const int rowbase = bm * 128 + 64 * wm;
#pragma unroll
  for (int nj = 0; nj < 4; nj++) {
    int col = colbase + 16 * nj + lr;
    float bv = bias[col];
#pragma unroll
    for (int mi = 0; mi < 4; mi++) {
#pragma unroll
      for (int r = 0; r < 4; r++) {
        size_t row = rowbase + 16 * mi + 4 * lg + r;
        float v = acc[mi][nj][r] + bv + x[row * CH + col];
        Y[row * CH + col] = __float2bfloat16(v);
      }
    }
  }
}

// ---------------- kernel 4: LayerNorm ----------------
__global__ __launch_bounds__(256) void ln_kernel(
    const bf16* __restrict__ Y, const float* __restrict__ g,
    const float* __restrict__ be, float* __restrict__ out)
{
  const int w = threadIdx.x >> 6, l = threadIdx.x & 63;
  const size_t r = (size_t)blockIdx.x * 4 + w;
  const bf16* yr = Y + r * CH;

  short8 a = *(const short8*)(yr + 8 * l);
  short4v b4 = *(const short4v*)(yr + 512 + 4 * l);
  float v[12];
#pragma unroll
  for (int j = 0; j < 8; j++) v[j] = bf2f(a[j]);
#pragma unroll
  for (int j = 0; j < 4; j++) v[8 + j] = bf2f(b4[j]);

  float s1 = 0.f, s2 = 0.f;
#pragma unroll
  for (int j = 0; j < 12; j++) { s1 += v[j]; s2 += v[j] * v[j]; }
#pragma unroll
  for (int m = 1; m <= 32; m <<= 1) {
    s1 += __shfl_xor(s1, m, 64);
    s2 += __shfl_xor(s2, m, 64);
  }
  float mu = s1 * (1.0f / 768.0f);
  float var = s2 * (1.0f / 768.0f) - mu * mu;
  float rs = rsqrtf(var + 1e-5f);

  float4 g0 = *(const float4*)(g + 8 * l);
  float4 g1 = *(const float4*)(g + 8 * l + 4);
  float4 g2 = *(const float4*)(g + 512 + 4 * l);
  float4 b0 = *(const float4*)(be + 8 * l);
  float4 b1 = *(const float4*)(be + 8 * l + 4);
  float4 b2 = *(const float4*)(be + 512 + 4 * l);

  float4 o0, o1, o2;
  o0.x = (v[0] - mu) * rs * g0.x + b0.x;
  o0.y = (v[1] - mu) * rs * g0.y + b0.y;
  o0.z = (v[2] - mu) * rs * g0.z + b0.z;
  o0.w = (v[3] - mu) * rs * g0.w + b0.w;
  o1.x = (v[4] - mu) * rs * g1.x + b1.x;
  o1.y = (v[5] - mu) * rs * g1.y + b1.y;
  o1.z = (v[6] - mu) * rs * g1.z + b1.z;
  o1.w = (v[7] - mu) * rs * g1.w + b1.w;
  o2.x = (v[8] - mu) * rs * g2.x + b2.x;
  o2.y = (v[9] - mu) * rs * g2.y + b2.y;
  o2.z = (v[10] - mu) * rs * g2.z + b2.z;
  o2.w = (v[11] - mu) * rs * g2.w + b2.w;

  float* orow = out + r * CH;
  *(float4*)(orow + 8 * l) = o0;
  *(float4*)(orow + 8 * l + 4) = o1;
  *(float4*)(orow + 512 + 4 * l) = o2;
}

// ---------------- launch ----------------
extern "C" void kernel_launch(void* const* d_in, const int* in_sizes, int n_in,
                              void* d_out, int out_size, void* d_ws, size_t ws_size,
                              hipStream_t stream) {
  (void)in_sizes; (void)n_in; (void)out_size; (void)ws_size;
  const float* x     = (const float*)d_in[0];
  const float* smask = (const float*)d_in[1];
  const float* wqkv  = (const float*)d_in[2];
  const float* bqkv  = (const float*)d_in[3];
  const float* wproj = (const float*)d_in[4];
  const float* bproj = (const float*)d_in[5];
  const float* table = (const float*)d_in[6];
  const float* lng   = (const float*)d_in[7];
  const float* lnb   = (const float*)d_in[8];
  const int*   rpi   = (const int*)d_in[9];
  float* out = (float*)d_out;

  char* ws = (char*)d_ws;
  bf16*  xb   = (bf16*)(ws);                      // 77,070,336 B
  bf16*  wqb  = (bf16*)(ws + 77070336);           //  3,538,944 B
  bf16*  wpb  = (bf16*)(ws + 80609280);           //  1,179,648 B
  float* comb = (float*)(ws + 81788928);          // 14,745,600 B
  bf16*  qkvT = (bf16*)(ws + 96534528);           // 231,211,008 B
  bf16*  aout = (bf16*)(ws + 327745536);          // 77,070,336 B
  bf16*  yb   = (bf16*)(ws + 96534528);           // aliases qkvT (dead after attn)

  cvt_bf16<<<37632, 256, 0, stream>>>(x, xb, 9633792);
  cvt_bf16<<<1728, 256, 0, stream>>>(wqkv, wqb, 442368);
  cvt_bf16<<<576, 256, 0, stream>>>(wproj, wpb, 147456);
  build_comb<<<14400, 256, 0, stream>>>(table, rpi, smask, comb);
  qkv_gemm<<<7056, 256, 0, stream>>>(xb, wqb, bqkv, qkvT);
  attn_kernel<<<dim3(1024, 6), 256, 0, stream>>>(qkvT, comb, aout);
  proj_gemm<<<2352, 256, 0, stream>>>(aout, wpb, bproj, x, yb);
  ln_kernel<<<12544, 256, 0, stream>>>(yb, lng, lnb, out);
}